// Round 10
// baseline (198.884 us; speedup 1.0000x reference)
//
#include <hip/hip_runtime.h>
#include <hip/hip_bf16.h>
#include <stdint.h>

// Problem constants: x[2,2048,1024], H=16, Dh=64
#define MROWS 4096   // B*T
#define DMODEL 1024
#define NQKV 3072
#define TSEQ 2048

typedef __attribute__((ext_vector_type(8))) short short8;   // 8 bf16 = 4 VGPRs
typedef __attribute__((ext_vector_type(4))) short short4v;  // 4 bf16 = 2 VGPRs
typedef __attribute__((ext_vector_type(4))) float floatx4;  // MFMA C/D
typedef unsigned short ushort_t;

// K/V tiled layouts for glds staging: [bh][32 tiles][64 rows][72] bf16.
#define TILE_ELEMS 4608        // 64*72
#define STEP_ELEMS 9216        // two stacked 64-key tiles = one 128-key step
#define BH_TILE_STRIDE 147456  // 32*4608

// Q pre-scale: (1/sqrt(64)) * log2(e) -- attention softmax runs in base 2.
#define QSCALE 0.1803368801111204f

static __device__ __forceinline__ unsigned short f2bf(float f) {
    union { float f; unsigned u; } v; v.f = f;
    unsigned r = v.u + 0x7fff + ((v.u >> 16) & 1);   // RNE
    return (unsigned short)(r >> 16);
}

// --- target-specific intrinsic wrappers -------------------------------------
// hipcc compiles this TU twice (device gfx950 + host x86). Host pass must
// PARSE device code but never executes it; gate amdgcn-only builtins on
// __HIP_DEVICE_COMPILE__ so the host pass gets plain-C fallbacks.

// D = A*B + C, 16x16x16 bf16 (A,B: 4 bf16/lane; C/D: 4 fp32/lane)
static __device__ __forceinline__ floatx4 mfma16(short4v a, short4v b, floatx4 c) {
#if defined(__HIP_DEVICE_COMPILE__)
#if __has_builtin(__builtin_amdgcn_mfma_f32_16x16x16bf16_1k)
    return __builtin_amdgcn_mfma_f32_16x16x16bf16_1k(a, b, c, 0, 0, 0);
#else
#error "mfma 16x16x16 bf16 builtin unavailable on device"
#endif
#else
    return c;   // host pass: parse-only, never executed
#endif
}

// pack two fp32 -> two bf16 (round-half-up): low16 = bf16(a), high16 = bf16(b).
static __device__ __forceinline__ unsigned pk2bf(float a, float b) {
    unsigned ua = __float_as_uint(a) + 0x8000u;
    unsigned ub = __float_as_uint(b) + 0x8000u;
#if defined(__HIP_DEVICE_COMPILE__) && __has_builtin(__builtin_amdgcn_perm)
    return __builtin_amdgcn_perm(ub, ua, 0x07060302u);  // {ub.b3,ub.b2,ua.b3,ua.b2}
#else
    return (ua >> 16) | (ub & 0xFFFF0000u);
#endif
}

static __device__ __forceinline__ float exp2_fast(float x) {
#if defined(__HIP_DEVICE_COMPILE__) && __has_builtin(__builtin_amdgcn_exp2f)
    return __builtin_amdgcn_exp2f(x);
#else
    return exp2f(x);
#endif
}

// async global->LDS, 16B per lane. Global addr must be PER-LANE; LDS dest is
// wave-uniform base + lane*16.
static __device__ __forceinline__ void glds16(const void* g, void* l) {
    __builtin_amdgcn_global_load_lds(
        (const __attribute__((address_space(1))) void*)g,
        (__attribute__((address_space(3))) void*)l, 16, 0, 0);
}

// ---------------- cast fp32 -> bf16 (n multiple of 4) ----------------
__global__ void cast_f32_bf16(const float* __restrict__ in,
                              ushort_t* __restrict__ out, int n) {
    int i = (blockIdx.x * blockDim.x + threadIdx.x) * 4;
    if (i < n) {
        float4 f = *(const float4*)(in + i);
        ushort4 o;
        o.x = f2bf(f.x); o.y = f2bf(f.y); o.z = f2bf(f.z); o.w = f2bf(f.w);
        *(ushort4*)(out + i) = o;
    }
}

// ---------------- transpose + cast: in[R][C] f32 -> out[C][R] bf16 ----------------
__global__ void transpose_cast(const float* __restrict__ in,
                               ushort_t* __restrict__ out, int R, int C) {
    __shared__ float tile[32][33];
    int c0 = blockIdx.x * 32, r0 = blockIdx.y * 32;
    int tx = threadIdx.x & 31, ty = threadIdx.x >> 5;
    for (int i = 0; i < 4; i++) {
        int r = ty + i * 8;
        tile[r][tx] = in[(size_t)(r0 + r) * C + c0 + tx];
    }
    __syncthreads();
    for (int i = 0; i < 4; i++) {
        int r = ty + i * 8;
        out[(size_t)(c0 + r) * R + r0 + tx] = f2bf(tile[tx][r]);
    }
}

// ---------------- V transpose: Vb [bh][2048][64] -> Vt [bh][32][64][72] ----------
// Column PERMUTATION baked in: source key s = 16*SB + 4*Q + J is stored at
// col' = 16*Q + 4*SB + J, so attn's PV A-fragment reads (k = quad*4+j over
// 4 sb blocks) land on 16 consecutive ushorts -> two ds_read_b128 per d-tile.
__global__ void transpose_v(const ushort_t* __restrict__ in,
                            ushort_t* __restrict__ out) {
    __shared__ ushort_t T[64][72];
    int tile = blockIdx.x, bh = blockIdx.y;
    int tid = threadIdx.x;
    int row = tid >> 2, q4 = tid & 3;
    const ushort_t* ip = in + ((size_t)bh * TSEQ + tile * 64) * 64;
#pragma unroll
    for (int p = 0; p < 2; p++) {
        int c = q4 * 16 + p * 8;
        *(uint4*)(&T[row][c]) = *(const uint4*)(ip + (size_t)row * 64 + c);
    }
    __syncthreads();
    ushort_t* op = out + (size_t)bh * BH_TILE_STRIDE + (size_t)tile * TILE_ELEMS;
#pragma unroll
    for (int p = 0; p < 2; p++) {
        int cbase = q4 * 16 + p * 8;          // c' chunk base
        ushort_t tmp[8];
#pragma unroll
        for (int e = 0; e < 8; e++) {
            int cp = cbase + e;               // c' = 16*Q + 4*SB + J
            int Q = cp >> 4, SB = (cp >> 2) & 3, J = cp & 3;
            int s = SB * 16 + Q * 4 + J;
            tmp[e] = T[s][row];               // row = d
        }
        *(uint4*)(op + (size_t)row * 72 + cbase) = *(uint4*)tmp;
    }
}

// ---------------- GEMM (m97 structure, BK=32 — round-7 proven) ----------------
// C = A[M][K] @ Bt[N][K]^T + bias.
// EPI 0: fp32 out0[M][N] + bias.
// EPI 1: Q -> [bh][t][64] bf16 scaled by QSCALE; K -> tiled [bh][32][64][72];
//        V -> [bh][t][64] bf16.
template <int EPI, int MFRAG>
__global__ __launch_bounds__(256, 2)
void gemm_glds(const ushort_t* __restrict__ A,
               const ushort_t* __restrict__ Bt,
               const float* __restrict__ bias,
               void* __restrict__ out0, void* __restrict__ out1, void* __restrict__ out2,
               int M, int N, int K) {
    __shared__ ushort_t As[MFRAG * 32 * 32];
    __shared__ ushort_t Bs[128 * 32];
    int tid = threadIdx.x;
    int wave = tid >> 6, lane = tid & 63;
    int quad = lane >> 4, l16 = lane & 15;
    int m0 = blockIdx.y * (MFRAG * 32), n0 = blockIdx.x * 128;
    int wm = (wave & 1) * (MFRAG * 16), wn = (wave >> 1) * 64;

    const floatx4 zero = {0.f, 0.f, 0.f, 0.f};
    floatx4 acc[MFRAG][4];
#pragma unroll
    for (int i = 0; i < MFRAG; i++)
#pragma unroll
        for (int j = 0; j < 4; j++) acc[i][j] = zero;

    int srow = tid >> 2, sc = tid & 3;
    const ushort_t* ag = A  + (size_t)(m0 + srow) * K + sc * 8;
    const ushort_t* bg = Bt + (size_t)(n0 + srow) * K + sc * 8;
    ushort_t* asw = As + wave * 512;
    ushort_t* bsw = Bs + wave * 512;

    for (int k0 = 0; k0 < K; k0 += 32) {
        glds16(ag + k0, asw);
        if (MFRAG == 4) glds16(ag + (size_t)64 * K + k0, asw + 2048);
        glds16(bg + k0, bsw);
        glds16(bg + (size_t)64 * K + k0, bsw + 2048);
        __syncthreads();
        short8 af[MFRAG], bf[4];
#pragma unroll
        for (int i = 0; i < MFRAG; i++)
            af[i] = *(const short8*)(As + (wm + i * 16 + l16) * 32 + quad * 8);
#pragma unroll
        for (int j = 0; j < 4; j++)
            bf[j] = *(const short8*)(Bs + (wn + j * 16 + l16) * 32 + quad * 8);
#pragma unroll
        for (int i = 0; i < MFRAG; i++)
#pragma unroll
            for (int j = 0; j < 4; j++)
                acc[i][j] = __builtin_amdgcn_mfma_f32_16x16x32_bf16(
                    af[i], bf[j], acc[i][j], 0, 0, 0);
        __syncthreads();
    }

    int sec = n0 >> 10;   // block-uniform (EPI==1): 0=Q, 1=K, 2=V
    ushort_t* dst = (ushort_t*)(sec == 0 ? out0 : (sec == 1 ? out1 : out2));
#pragma unroll
    for (int i = 0; i < MFRAG; i++) {
        int row = m0 + wm + i * 16 + quad * 4;
#pragma unroll
        for (int j = 0; j < 4; j++) {
            int col = n0 + wn + j * 16 + l16;
            float bvs = bias[col];
#pragma unroll
            for (int r = 0; r < 4; r++) {
                float v = acc[i][j][r] + bvs;
                int rowr = row + r;
                if (EPI == 0) {
                    ((float*)out0)[(size_t)rowr * N + col] = v;
                } else {
                    int b = rowr >> 11, t = rowr & 2047;
                    int within = col & 1023, h = within >> 6, d = within & 63;
                    size_t bh = (size_t)(b * 16 + h);
                    if (sec == 0)
                        dst[(bh * 2048 + t) * 64 + d] = f2bf(v * QSCALE);
                    else if (sec == 1)
                        dst[bh * BH_TILE_STRIDE + (size_t)(t >> 6) * TILE_ELEMS
                            + (size_t)(t & 63) * 72 + d] = f2bf(v);
                    else
                        dst[(bh * 2048 + t) * 64 + d] = f2bf(v);
                }
            }
        }
    }
}

// ---------------- flash attention (causal), S^T, base-2 softmax, 128-key steps ---
// Q: [bh][t][64] (pre-scaled by QSCALE). Kt: [bh][32][64][72] tiled.
// Vt: [bh][32][64][72] tiled with column permutation (see transpose_v).
// out: [b*2048+t][h*64+d] bf16.
// Block = (bh, pair): q-tiles {pair, 31-pair}; 128-key steps (two stacked
// 64-tiles per LDS buffer) -> 17 barriers/block instead of 33. No max-shift
// (scores tightly bounded): p = 2^s, l = plain sum reduced once at epilogue.
// Even-qt tiles waste one fully-masked 64-key sub-tile on their last step (~3%)
// to keep all loops static (dynamic reg-array trip counts spill — round 2/3).
__global__ __launch_bounds__(256, 1)
void attn_kernel(const ushort_t* __restrict__ Qb,
                 const ushort_t* __restrict__ Kt,
                 const ushort_t* __restrict__ Vt,
                 ushort_t* __restrict__ outb) {
    __shared__ ushort_t Ks[2][128 * 72];   // [key 0..127][d] (two stacked tiles)
    __shared__ ushort_t Vs[2][128 * 72];   // rows: tile0 d=0..63, tile1 d=64..127
    int tid = threadIdx.x;
    int wave = tid >> 6, lane = tid & 63;
    int quad = lane >> 4, l16 = lane & 15;
    int pair = blockIdx.x;   // 0..15
    int bh = blockIdx.y;     // 0..31
    int b = bh >> 4, h = bh & 15;
    const ushort_t* qh = Qb + (size_t)bh * TSEQ * 64;
    const ushort_t* kh = Kt + (size_t)bh * BH_TILE_STRIDE;
    const ushort_t* vh = Vt + (size_t)bh * BH_TILE_STRIDE;
    const floatx4 zero = {0.f, 0.f, 0.f, 0.f};
    int lo8 = lane * 8;   // per-lane 16B offset for glds global addresses

    for (int half = 0; half < 2; half++) {
        int qt = half ? (31 - pair) : pair;
        int q0 = qt * 64;
        int nsteps = (qt + 2) >> 1;   // 128-key steps; covers (qt+1)*64 keys (+pad)

        // Q fragments; layout serves as A (m=l16) or B (n=l16), k=quad*8+j(+32).
        int qrow = q0 + wave * 16 + l16;
        short8 qf0 = *(const short8*)(qh + (size_t)qrow * 64 + quad * 8);
        short8 qf1 = *(const short8*)(qh + (size_t)qrow * 64 + 32 + quad * 8);

        floatx4 Oacc[4];
#pragma unroll
        for (int j = 0; j < 4; j++) Oacc[j] = zero;
        float lsum = 0.f;   // lane-local partial denominator

        // preload step 0 -> buffer 0 (18 KB each = 18 x 1KB glds, split by wave)
#pragma unroll
        for (int c = 0; c < 5; c++) {
            int cc = wave + 4 * c;
            if (cc < 18) {
                glds16(kh + cc * 512 + lo8, &Ks[0][cc * 512]);
                glds16(vh + cc * 512 + lo8, &Vs[0][cc * 512]);
            }
        }

        for (int step = 0; step < nsteps; step++) {
            int cur = step & 1;
            __syncthreads();
            if (step + 1 < nsteps) {   // prefetch next 128-key step
                const ushort_t* kt = kh + (size_t)(step + 1) * STEP_ELEMS;
                const ushort_t* vt = vh + (size_t)(step + 1) * STEP_ELEMS;
#pragma unroll
                for (int c = 0; c < 5; c++) {
                    int cc = wave + 4 * c;
                    if (cc < 18) {
                        glds16(kt + cc * 512 + lo8, &Ks[cur ^ 1][cc * 512]);
                        glds16(vt + cc * 512 + lo8, &Vs[cur ^ 1][cc * 512]);
                    }
                }
            }
            const ushort_t* ks = &Ks[cur][0];
            const ushort_t* vs = &Vs[cur][0];

            // S^T = K Q^T : D col = q = l16, row = s_local = sb*16 + quad*4 + reg.
            floatx4 S[8];
#pragma unroll
            for (int sb = 0; sb < 8; sb++) {
                short8 kf0 = *(const short8*)(ks + (sb * 16 + l16) * 72 + quad * 8);
                short8 kf1 = *(const short8*)(ks + (sb * 16 + l16) * 72 + 32 + quad * 8);
                floatx4 s = zero;
                s = __builtin_amdgcn_mfma_f32_16x16x32_bf16(kf0, qf0, s, 0, 0, 0);
                s = __builtin_amdgcn_mfma_f32_16x16x32_bf16(kf1, qf1, s, 0, 0, 0);
                S[sb] = s;
            }
            // causal mask, last step only: s_global > q_global.
            // dq = s0 - q0 is 0 (even qt) or -64 (odd qt).
            if (step == nsteps - 1) {
                int ql = wave * 16 + l16;
                int dq = step * 128 - q0;
#pragma unroll
                for (int sb = 0; sb < 8; sb++)
#pragma unroll
                    for (int r = 0; r < 4; r++)
                        if (dq + sb * 16 + quad * 4 + r > ql) S[sb][r] = -1e30f;
            }
            // p = 2^s (log2e folded into Q scale); accumulate lane-local l
            float sum = 0.f;
#pragma unroll
            for (int sb = 0; sb < 8; sb++)
#pragma unroll
                for (int r = 0; r < 4; r++) {
                    float p = exp2_fast(S[sb][r]);   // 2^(-1e30) == 0 for masked
                    S[sb][r] = p;
                    sum += p;
                }
            lsum += sum;

            // P^T B-frags: pack pairs via v_perm; B[k=quad*4+j][n=l16] = S[sb][j]
            short4v pf[8];
#pragma unroll
            for (int sb = 0; sb < 8; sb++) {
                union { unsigned u[2]; short4v v; } pk;
                pk.u[0] = pk2bf(S[sb][0], S[sb][1]);
                pk.u[1] = pk2bf(S[sb][2], S[sb][3]);
                pf[sb] = pk.v;
            }
            // O^T += V^T P^T : A[m=d][k]; keys 0-63 in Vs rows [0,64) (sb0-3),
            // keys 64-127 in rows [64,128) (sb4-7); perm makes each a b128 pair.
#pragma unroll
            for (int jd = 0; jd < 4; jd++) {
                const ushort_t* vr0 = vs + (jd * 16 + l16) * 72 + quad * 16;
                const ushort_t* vr1 = vr0 + 64 * 72;
                short8 vA = *(const short8*)(vr0);       // sb0 | sb1
                short8 vB = *(const short8*)(vr0 + 8);   // sb2 | sb3
                short8 vC = *(const short8*)(vr1);       // sb4 | sb5
                short8 vD = *(const short8*)(vr1 + 8);   // sb6 | sb7
                Oacc[jd] = mfma16(__builtin_shufflevector(vA, vA, 0, 1, 2, 3), pf[0], Oacc[jd]);
                Oacc[jd] = mfma16(__builtin_shufflevector(vA, vA, 4, 5, 6, 7), pf[1], Oacc[jd]);
                Oacc[jd] = mfma16(__builtin_shufflevector(vB, vB, 0, 1, 2, 3), pf[2], Oacc[jd]);
                Oacc[jd] = mfma16(__builtin_shufflevector(vB, vB, 4, 5, 6, 7), pf[3], Oacc[jd]);
                Oacc[jd] = mfma16(__builtin_shufflevector(vC, vC, 0, 1, 2, 3), pf[4], Oacc[jd]);
                Oacc[jd] = mfma16(__builtin_shufflevector(vC, vC, 4, 5, 6, 7), pf[5], Oacc[jd]);
                Oacc[jd] = mfma16(__builtin_shufflevector(vD, vD, 0, 1, 2, 3), pf[6], Oacc[jd]);
                Oacc[jd] = mfma16(__builtin_shufflevector(vD, vD, 4, 5, 6, 7), pf[7], Oacc[jd]);
            }
        }
        // epilogue: reduce l across quads (once), O^T / l -> ushort4 stores
        {
            float l = lsum;
            l += __shfl_xor(l, 16);
            l += __shfl_xor(l, 32);
            float rl = 1.0f / l;
            int row = b * TSEQ + q0 + wave * 16 + l16;
#pragma unroll
            for (int jd = 0; jd < 4; jd++) {
                int col = h * 64 + jd * 16 + quad * 4;
                ushort4 o;
                o.x = f2bf(Oacc[jd][0] * rl);
                o.y = f2bf(Oacc[jd][1] * rl);
                o.z = f2bf(Oacc[jd][2] * rl);
                o.w = f2bf(Oacc[jd][3] * rl);
                *(ushort4*)(outb + (size_t)row * DMODEL + col) = o;
            }
        }
        __syncthreads();   // protect next half's buffer-0 preload vs this half's reads
    }
}

extern "C" void kernel_launch(void* const* d_in, const int* in_sizes, int n_in,
                              void* d_out, int out_size, void* d_ws, size_t ws_size,
                              hipStream_t stream) {
    const float* x      = (const float*)d_in[0];
    const float* w_qkv  = (const float*)d_in[1];
    const float* b_qkv  = (const float*)d_in[2];
    const float* w_proj = (const float*)d_in[3];
    const float* b_proj = (const float*)d_in[4];
    float* out = (float*)d_out;
    char* ws = (char*)d_ws;

    // workspace (39 MB peak), phased reuse:
    //  [0,8M):        xb (x bf16)       -> Vt tiled [0,9437184) after QKV GEMM
    //  [8M,14M):      wqkvT             -> dead after QKV GEMM; wprojT lives at 10M
    //  [14680064,+8M): Qb   [bh][2048][64]
    //  [23068672,+9M): Kt   [bh][32][64][72] tiled
    //  [32505856,+8M): Vb   [bh][2048][64]  -> attnb after transpose_v
    ushort_t* xb     = (ushort_t*)(ws);
    ushort_t* Vt     = (ushort_t*)(ws);
    ushort_t* wqkvT  = (ushort_t*)(ws + 8388608);
    ushort_t* wprojT = (ushort_t*)(ws + 10485760);
    ushort_t* Qb     = (ushort_t*)(ws + 14680064);
    ushort_t* Kt     = (ushort_t*)(ws + 23068672);
    ushort_t* Vb     = (ushort_t*)(ws + 32505856);
    ushort_t* attnb  = Vb;

    cast_f32_bf16<<<4096, 256, 0, stream>>>(x, xb, MROWS * DMODEL);
    transpose_cast<<<dim3(NQKV / 32, DMODEL / 32), 256, 0, stream>>>(w_qkv, wqkvT, DMODEL, NQKV);

    gemm_glds<1, 4><<<dim3(NQKV / 128, MROWS / 128), 256, 0, stream>>>(
        xb, wqkvT, b_qkv, Qb, Kt, Vb, MROWS, NQKV, DMODEL);

    transpose_v<<<dim3(32, 32), 256, 0, stream>>>(Vb, Vt);
    // wprojT region (inside dead wqkvT) safe to write now
    transpose_cast<<<dim3(DMODEL / 32, DMODEL / 32), 256, 0, stream>>>(w_proj, wprojT, DMODEL, DMODEL);

    attn_kernel<<<dim3(16, 32), 256, 0, stream>>>(Qb, Kt, Vt, attnb);

    gemm_glds<0, 2><<<dim3(DMODEL / 128, MROWS / 64), 256, 0, stream>>>(
        attnb, wprojT, b_proj, out, nullptr, nullptr, MROWS, DMODEL, DMODEL);
}

// Round 11
// 194.746 us; speedup vs baseline: 1.0213x; 1.0213x over previous
//
#include <hip/hip_runtime.h>
#include <hip/hip_bf16.h>
#include <stdint.h>

// Problem constants: x[2,2048,1024], H=16, Dh=64
#define MROWS 4096   // B*T
#define DMODEL 1024
#define NQKV 3072
#define TSEQ 2048

typedef __attribute__((ext_vector_type(8))) short short8;   // 8 bf16 = 4 VGPRs
typedef __attribute__((ext_vector_type(4))) short short4v;  // 4 bf16 = 2 VGPRs
typedef __attribute__((ext_vector_type(4))) float floatx4;  // MFMA C/D
typedef unsigned short ushort_t;

// K/V tiled layouts for glds staging: [bh][32 tiles][64 rows][72] bf16.
#define TILE_ELEMS 4608        // 64*72
#define BH_TILE_STRIDE 147456  // 32*4608

// Q pre-scale: (1/sqrt(64)) * log2(e) -- attention softmax runs in base 2.
#define QSCALE 0.1803368801111204f

static __device__ __forceinline__ unsigned short f2bf(float f) {
    union { float f; unsigned u; } v; v.f = f;
    unsigned r = v.u + 0x7fff + ((v.u >> 16) & 1);   // RNE
    return (unsigned short)(r >> 16);
}

// --- target-specific intrinsic wrappers -------------------------------------
// hipcc compiles this TU twice (device gfx950 + host x86). Host pass must
// PARSE device code but never executes it; gate amdgcn-only builtins on
// __HIP_DEVICE_COMPILE__ so the host pass gets plain-C fallbacks.

// D = A*B + C, 16x16x16 bf16 (A,B: 4 bf16/lane; C/D: 4 fp32/lane)
static __device__ __forceinline__ floatx4 mfma16(short4v a, short4v b, floatx4 c) {
#if defined(__HIP_DEVICE_COMPILE__)
#if __has_builtin(__builtin_amdgcn_mfma_f32_16x16x16bf16_1k)
    return __builtin_amdgcn_mfma_f32_16x16x16bf16_1k(a, b, c, 0, 0, 0);
#else
#error "mfma 16x16x16 bf16 builtin unavailable on device"
#endif
#else
    return c;   // host pass: parse-only, never executed
#endif
}

// pack two fp32 -> two bf16 (round-half-up): low16 = bf16(a), high16 = bf16(b).
static __device__ __forceinline__ unsigned pk2bf(float a, float b) {
    unsigned ua = __float_as_uint(a) + 0x8000u;
    unsigned ub = __float_as_uint(b) + 0x8000u;
#if defined(__HIP_DEVICE_COMPILE__) && __has_builtin(__builtin_amdgcn_perm)
    return __builtin_amdgcn_perm(ub, ua, 0x07060302u);  // {ub.b3,ub.b2,ua.b3,ua.b2}
#else
    return (ua >> 16) | (ub & 0xFFFF0000u);
#endif
}

static __device__ __forceinline__ float exp2_fast(float x) {
#if defined(__HIP_DEVICE_COMPILE__) && __has_builtin(__builtin_amdgcn_exp2f)
    return __builtin_amdgcn_exp2f(x);
#else
    return exp2f(x);
#endif
}

// async global->LDS, 16B per lane. Global addr must be PER-LANE; LDS dest is
// wave-uniform base + lane*16.
static __device__ __forceinline__ void glds16(const void* g, void* l) {
    __builtin_amdgcn_global_load_lds(
        (const __attribute__((address_space(1))) void*)g,
        (__attribute__((address_space(3))) void*)l, 16, 0, 0);
}

// ---------------- cast fp32 -> bf16 (n multiple of 4) ----------------
__global__ void cast_f32_bf16(const float* __restrict__ in,
                              ushort_t* __restrict__ out, int n) {
    int i = (blockIdx.x * blockDim.x + threadIdx.x) * 4;
    if (i < n) {
        float4 f = *(const float4*)(in + i);
        ushort4 o;
        o.x = f2bf(f.x); o.y = f2bf(f.y); o.z = f2bf(f.z); o.w = f2bf(f.w);
        *(ushort4*)(out + i) = o;
    }
}

// ---------------- transpose + cast: in[R][C] f32 -> out[C][R] bf16 ----------------
__global__ void transpose_cast(const float* __restrict__ in,
                               ushort_t* __restrict__ out, int R, int C) {
    __shared__ float tile[32][33];
    int c0 = blockIdx.x * 32, r0 = blockIdx.y * 32;
    int tx = threadIdx.x & 31, ty = threadIdx.x >> 5;
    for (int i = 0; i < 4; i++) {
        int r = ty + i * 8;
        tile[r][tx] = in[(size_t)(r0 + r) * C + c0 + tx];
    }
    __syncthreads();
    for (int i = 0; i < 4; i++) {
        int r = ty + i * 8;
        out[(size_t)(c0 + r) * R + r0 + tx] = f2bf(tile[tx][r]);
    }
}

// ---------------- V transpose: Vb [bh][2048][64] -> Vt [bh][32][64][72] ----------
// Column PERMUTATION baked in: source key s = 16*SB + 4*Q + J is stored at
// col' = 16*Q + 4*SB + J, so attn's PV A-fragment reads (k = quad*4+j over
// 4 sb blocks) land on 16 consecutive ushorts -> two ds_read_b128 per d-tile.
__global__ void transpose_v(const ushort_t* __restrict__ in,
                            ushort_t* __restrict__ out) {
    __shared__ ushort_t T[64][72];
    int tile = blockIdx.x, bh = blockIdx.y;
    int tid = threadIdx.x;
    int row = tid >> 2, q4 = tid & 3;
    const ushort_t* ip = in + ((size_t)bh * TSEQ + tile * 64) * 64;
#pragma unroll
    for (int p = 0; p < 2; p++) {
        int c = q4 * 16 + p * 8;
        *(uint4*)(&T[row][c]) = *(const uint4*)(ip + (size_t)row * 64 + c);
    }
    __syncthreads();
    ushort_t* op = out + (size_t)bh * BH_TILE_STRIDE + (size_t)tile * TILE_ELEMS;
#pragma unroll
    for (int p = 0; p < 2; p++) {
        int cbase = q4 * 16 + p * 8;          // c' chunk base
        ushort_t tmp[8];
#pragma unroll
        for (int e = 0; e < 8; e++) {
            int cp = cbase + e;               // c' = 16*Q + 4*SB + J
            int Q = cp >> 4, SB = (cp >> 2) & 3, J = cp & 3;
            int s = SB * 16 + Q * 4 + J;
            tmp[e] = T[s][row];               // row = d
        }
        *(uint4*)(op + (size_t)row * 72 + cbase) = *(uint4*)tmp;
    }
}

// ---------------- GEMM (m97 structure, BK=32), XCD-swizzled 1-D grid ----------
// C = A[M][K] @ Bt[N][K]^T + bias.
// Block mapping: id -> xcd = id&7 (blockIdx%8 is the XCD heuristic), each XCD
// owns PERXCD consecutive m-tiles and sweeps all n-tiles, so its A working set
// (PERXCD x 256 KB) stays L2-resident across the n-sweep.
// EPI 0: fp32 out0[M][N] + bias.
// EPI 1: Q -> [bh][t][64] bf16 scaled by QSCALE; K -> tiled [bh][32][64][72];
//        V -> [bh][t][64] bf16.
template <int EPI, int MFRAG, int PERXCD>
__global__ __launch_bounds__(256, 3)
void gemm_glds(const ushort_t* __restrict__ A,
               const ushort_t* __restrict__ Bt,
               const float* __restrict__ bias,
               void* __restrict__ out0, void* __restrict__ out1, void* __restrict__ out2,
               int M, int N, int K) {
    __shared__ ushort_t As[MFRAG * 32 * 32];
    __shared__ ushort_t Bs[128 * 32];
    int tid = threadIdx.x;
    int wave = tid >> 6, lane = tid & 63;
    int quad = lane >> 4, l16 = lane & 15;
    // XCD swizzle (PERXCD is a power of two)
    int id = blockIdx.x;
    int xcd = id & 7, sidx = id >> 3;
    int m_idx = xcd * PERXCD + (sidx & (PERXCD - 1));
    int n_idx = sidx / PERXCD;
    int m0 = m_idx * (MFRAG * 32), n0 = n_idx * 128;
    int wm = (wave & 1) * (MFRAG * 16), wn = (wave >> 1) * 64;

    const floatx4 zero = {0.f, 0.f, 0.f, 0.f};
    floatx4 acc[MFRAG][4];
#pragma unroll
    for (int i = 0; i < MFRAG; i++)
#pragma unroll
        for (int j = 0; j < 4; j++) acc[i][j] = zero;

    int srow = tid >> 2, sc = tid & 3;
    const ushort_t* ag = A  + (size_t)(m0 + srow) * K + sc * 8;
    const ushort_t* bg = Bt + (size_t)(n0 + srow) * K + sc * 8;
    ushort_t* asw = As + wave * 512;
    ushort_t* bsw = Bs + wave * 512;

    for (int k0 = 0; k0 < K; k0 += 32) {
        glds16(ag + k0, asw);
        if (MFRAG == 4) glds16(ag + (size_t)64 * K + k0, asw + 2048);
        glds16(bg + k0, bsw);
        glds16(bg + (size_t)64 * K + k0, bsw + 2048);
        __syncthreads();
        short8 af[MFRAG], bf[4];
#pragma unroll
        for (int i = 0; i < MFRAG; i++)
            af[i] = *(const short8*)(As + (wm + i * 16 + l16) * 32 + quad * 8);
#pragma unroll
        for (int j = 0; j < 4; j++)
            bf[j] = *(const short8*)(Bs + (wn + j * 16 + l16) * 32 + quad * 8);
#pragma unroll
        for (int i = 0; i < MFRAG; i++)
#pragma unroll
            for (int j = 0; j < 4; j++)
                acc[i][j] = __builtin_amdgcn_mfma_f32_16x16x32_bf16(
                    af[i], bf[j], acc[i][j], 0, 0, 0);
        __syncthreads();
    }

    int sec = n0 >> 10;   // block-uniform (EPI==1): 0=Q, 1=K, 2=V
    ushort_t* dst = (ushort_t*)(sec == 0 ? out0 : (sec == 1 ? out1 : out2));
#pragma unroll
    for (int i = 0; i < MFRAG; i++) {
        int row = m0 + wm + i * 16 + quad * 4;
#pragma unroll
        for (int j = 0; j < 4; j++) {
            int col = n0 + wn + j * 16 + l16;
            float bvs = bias[col];
#pragma unroll
            for (int r = 0; r < 4; r++) {
                float v = acc[i][j][r] + bvs;
                int rowr = row + r;
                if (EPI == 0) {
                    ((float*)out0)[(size_t)rowr * N + col] = v;
                } else {
                    int b = rowr >> 11, t = rowr & 2047;
                    int within = col & 1023, h = within >> 6, d = within & 63;
                    size_t bh = (size_t)(b * 16 + h);
                    if (sec == 0)
                        dst[(bh * 2048 + t) * 64 + d] = f2bf(v * QSCALE);
                    else if (sec == 1)
                        dst[bh * BH_TILE_STRIDE + (size_t)(t >> 6) * TILE_ELEMS
                            + (size_t)(t & 63) * 72 + d] = f2bf(v);
                    else
                        dst[(bh * 2048 + t) * 64 + d] = f2bf(v);
                }
            }
        }
    }
}

// ---------------- flash attention (round-9 proven: 64-key steps) ----------------
// Q: [bh][t][64] (pre-scaled by QSCALE). Kt: [bh][32][64][72] tiled.
// Vt: [bh][32][64][72] tiled with column permutation (see transpose_v).
// out: [b*2048+t][h*64+d] bf16.
// Block = (bh, pair): q-tiles {pair, 31-pair} -> uniform 33 key-steps.
// S^T = K Q^T keeps P^T in registers as the PV B-operand; base-2 softmax with
// no max-shift (scores tightly bounded); l reduced across quads at epilogue.
__global__ __launch_bounds__(256, 1)
void attn_kernel(const ushort_t* __restrict__ Qb,
                 const ushort_t* __restrict__ Kt,
                 const ushort_t* __restrict__ Vt,
                 ushort_t* __restrict__ outb) {
    __shared__ ushort_t Ks[2][64 * 72];
    __shared__ ushort_t Vs[2][64 * 72];
    int tid = threadIdx.x;
    int wave = tid >> 6, lane = tid & 63;
    int quad = lane >> 4, l16 = lane & 15;
    int pair = blockIdx.x;   // 0..15
    int bh = blockIdx.y;     // 0..31
    int b = bh >> 4, h = bh & 15;
    const ushort_t* qh = Qb + (size_t)bh * TSEQ * 64;
    const ushort_t* kh = Kt + (size_t)bh * BH_TILE_STRIDE;
    const ushort_t* vh = Vt + (size_t)bh * BH_TILE_STRIDE;
    const floatx4 zero = {0.f, 0.f, 0.f, 0.f};
    int lo8 = lane * 8;   // per-lane 16B offset for glds global addresses

    for (int half = 0; half < 2; half++) {
        int qt = half ? (31 - pair) : pair;
        int q0 = qt * 64;
        int nsteps = qt + 1;

        // Q fragments; layout serves as A (m=l16) or B (n=l16), k=quad*8+j(+32).
        int qrow = q0 + wave * 16 + l16;
        short8 qf0 = *(const short8*)(qh + (size_t)qrow * 64 + quad * 8);
        short8 qf1 = *(const short8*)(qh + (size_t)qrow * 64 + 32 + quad * 8);

        floatx4 Oacc[4];
#pragma unroll
        for (int j = 0; j < 4; j++) Oacc[j] = zero;
        float lsum = 0.f;   // lane-local partial denominator

        // preload tile 0 -> buffer 0 (9 KB each = 9 x 1KB glds, split by wave)
#pragma unroll
        for (int c = 0; c < 3; c++) {
            int cc = wave + 4 * c;
            if (cc < 9) {
                glds16(kh + cc * 512 + lo8, &Ks[0][cc * 512]);
                glds16(vh + cc * 512 + lo8, &Vs[0][cc * 512]);
            }
        }

        for (int step = 0; step < nsteps; step++) {
            int cur = step & 1;
            __syncthreads();
            if (step + 1 < nsteps) {
                const ushort_t* kt = kh + (size_t)(step + 1) * TILE_ELEMS;
                const ushort_t* vt = vh + (size_t)(step + 1) * TILE_ELEMS;
#pragma unroll
                for (int c = 0; c < 3; c++) {
                    int cc = wave + 4 * c;
                    if (cc < 9) {
                        glds16(kt + cc * 512 + lo8, &Ks[cur ^ 1][cc * 512]);
                        glds16(vt + cc * 512 + lo8, &Vs[cur ^ 1][cc * 512]);
                    }
                }
            }
            const ushort_t* ks = &Ks[cur][0];
            const ushort_t* vs = &Vs[cur][0];

            // S^T = K Q^T : D col = q = l16, row = s_local = sb*16 + quad*4 + reg.
            floatx4 S[4];
#pragma unroll
            for (int sb = 0; sb < 4; sb++) {
                short8 kf0 = *(const short8*)(ks + (sb * 16 + l16) * 72 + quad * 8);
                short8 kf1 = *(const short8*)(ks + (sb * 16 + l16) * 72 + 32 + quad * 8);
                floatx4 s = zero;
                s = __builtin_amdgcn_mfma_f32_16x16x32_bf16(kf0, qf0, s, 0, 0, 0);
                s = __builtin_amdgcn_mfma_f32_16x16x32_bf16(kf1, qf1, s, 0, 0, 0);
                S[sb] = s;
            }
            // causal mask (diag step: s0 == q0): s_local > q_local(=wave*16+l16)
            if (step == nsteps - 1) {
                int ql = wave * 16 + l16;
#pragma unroll
                for (int sb = 0; sb < 4; sb++)
#pragma unroll
                    for (int r = 0; r < 4; r++)
                        if (sb * 16 + quad * 4 + r > ql) S[sb][r] = -1e30f;
            }
            // p = 2^s (log2e folded into Q scale); accumulate lane-local l
            float sum = 0.f;
#pragma unroll
            for (int sb = 0; sb < 4; sb++)
#pragma unroll
                for (int r = 0; r < 4; r++) {
                    float p = exp2_fast(S[sb][r]);   // 2^(-1e30) == 0 for masked
                    S[sb][r] = p;
                    sum += p;
                }
            lsum += sum;

            // P^T B-frags: pack pairs via v_perm; B[k=quad*4+j][n=l16] = S[sb][j]
            short4v pf[4];
#pragma unroll
            for (int sb = 0; sb < 4; sb++) {
                union { unsigned u[2]; short4v v; } pk;
                pk.u[0] = pk2bf(S[sb][0], S[sb][1]);
                pk.u[1] = pk2bf(S[sb][2], S[sb][3]);
                pf[sb] = pk.v;
            }
            // O^T += V^T P^T : A[m=d][k=quad*4+j]; permuted Vt makes the 4 sb
            // fragments 16 consecutive ushorts -> two b128 loads per d-tile.
#pragma unroll
            for (int jd = 0; jd < 4; jd++) {
                const ushort_t* vrow = vs + (jd * 16 + l16) * 72 + quad * 16;
                short8 vA = *(const short8*)(vrow);       // sb0 | sb1
                short8 vB = *(const short8*)(vrow + 8);   // sb2 | sb3
                short4v v0 = __builtin_shufflevector(vA, vA, 0, 1, 2, 3);
                short4v v1 = __builtin_shufflevector(vA, vA, 4, 5, 6, 7);
                short4v v2 = __builtin_shufflevector(vB, vB, 0, 1, 2, 3);
                short4v v3 = __builtin_shufflevector(vB, vB, 4, 5, 6, 7);
                Oacc[jd] = mfma16(v0, pf[0], Oacc[jd]);
                Oacc[jd] = mfma16(v1, pf[1], Oacc[jd]);
                Oacc[jd] = mfma16(v2, pf[2], Oacc[jd]);
                Oacc[jd] = mfma16(v3, pf[3], Oacc[jd]);
            }
        }
        // epilogue: reduce l across quads (once), O^T / l -> ushort4 stores
        {
            float l = lsum;
            l += __shfl_xor(l, 16);
            l += __shfl_xor(l, 32);
            float rl = 1.0f / l;
            int row = b * TSEQ + q0 + wave * 16 + l16;
#pragma unroll
            for (int jd = 0; jd < 4; jd++) {
                int col = h * 64 + jd * 16 + quad * 4;
                ushort4 o;
                o.x = f2bf(Oacc[jd][0] * rl);
                o.y = f2bf(Oacc[jd][1] * rl);
                o.z = f2bf(Oacc[jd][2] * rl);
                o.w = f2bf(Oacc[jd][3] * rl);
                *(ushort4*)(outb + (size_t)row * DMODEL + col) = o;
            }
        }
        __syncthreads();   // protect next half's buffer-0 preload vs this half's reads
    }
}

extern "C" void kernel_launch(void* const* d_in, const int* in_sizes, int n_in,
                              void* d_out, int out_size, void* d_ws, size_t ws_size,
                              hipStream_t stream) {
    const float* x      = (const float*)d_in[0];
    const float* w_qkv  = (const float*)d_in[1];
    const float* b_qkv  = (const float*)d_in[2];
    const float* w_proj = (const float*)d_in[3];
    const float* b_proj = (const float*)d_in[4];
    float* out = (float*)d_out;
    char* ws = (char*)d_ws;

    // workspace (39 MB peak), phased reuse:
    //  [0,8M):        xb (x bf16)       -> Vt tiled [0,9437184) after QKV GEMM
    //  [8M,14M):      wqkvT             -> dead after QKV GEMM; wprojT lives at 10M
    //  [14680064,+8M): Qb   [bh][2048][64]
    //  [23068672,+9M): Kt   [bh][32][64][72] tiled
    //  [32505856,+8M): Vb   [bh][2048][64]  -> attnb after transpose_v
    ushort_t* xb     = (ushort_t*)(ws);
    ushort_t* Vt     = (ushort_t*)(ws);
    ushort_t* wqkvT  = (ushort_t*)(ws + 8388608);
    ushort_t* wprojT = (ushort_t*)(ws + 10485760);
    ushort_t* Qb     = (ushort_t*)(ws + 14680064);
    ushort_t* Kt     = (ushort_t*)(ws + 23068672);
    ushort_t* Vb     = (ushort_t*)(ws + 32505856);
    ushort_t* attnb  = Vb;

    cast_f32_bf16<<<4096, 256, 0, stream>>>(x, xb, MROWS * DMODEL);
    transpose_cast<<<dim3(NQKV / 32, DMODEL / 32), 256, 0, stream>>>(w_qkv, wqkvT, DMODEL, NQKV);

    // QKV: 32 m-tiles (MFRAG=4) -> PERXCD=4; 24 n-tiles; 768 blocks 1-D.
    gemm_glds<1, 4, 4><<<768, 256, 0, stream>>>(
        xb, wqkvT, b_qkv, Qb, Kt, Vb, MROWS, NQKV, DMODEL);

    transpose_v<<<dim3(32, 32), 256, 0, stream>>>(Vb, Vt);
    // wprojT region (inside dead wqkvT) safe to write now
    transpose_cast<<<dim3(DMODEL / 32, DMODEL / 32), 256, 0, stream>>>(w_proj, wprojT, DMODEL, DMODEL);

    attn_kernel<<<dim3(16, 32), 256, 0, stream>>>(Qb, Kt, Vt, attnb);

    // proj: 64 m-tiles (MFRAG=2) -> PERXCD=8; 8 n-tiles; 512 blocks 1-D.
    gemm_glds<0, 2, 8><<<512, 256, 0, stream>>>(
        attnb, wprojT, b_proj, out, nullptr, nullptr, MROWS, DMODEL, DMODEL);
}